// Round 3
// baseline (412.929 us; speedup 1.0000x reference)
//
#include <hip/hip_runtime.h>
#include <math.h>

#define LMAX   5
#define MUL    128
#define NCH    4
#define NRAD   64
#define RBETA  180
#define RALPHA 359
#define NGRAPH 16
#define SH_DIM 36
#define EMB_DIM 4608
#define NIRR   768

#define GRID_BA (RBETA * RALPHA)          // 64620

// out layout (floats): [0] coeffs 147456 | [1] pos 66170880 | [2] ang 1033920 | [3] rad 1024
#define OUT0_OFF 0
#define OUT1_OFF 147456
#define OUT2_OFF (147456 + 66170880)
#define OUT3_OFF (147456 + 66170880 + 1033920)

// ws layout: float sWtab[180*21] @0 ; float ang[16*144] @16384B ; float rad[16*64] @26624B

// ---------------------------------------------------------------------------
// K1: per-beta prep. Thread i: Gauss-Legendre node i of P_180 (Newton, fp64,
// division-free scaled recurrence S_{k+1}=(2k+1)x S_k - k^2 S_{k-1}, S_j=j!P_j;
// only the ratio P_n/P_{n-1} enters Newton so the scale cancels), then the 21
// per-beta SH weights  w[l,m] = (m?sqrt2:1) * N_lm * P_lm(y_i).
__global__ __launch_bounds__(192)
void k_prep(float* __restrict__ sWtab) {
    const int i = threadIdx.x;
    if (i >= RBETA) return;
    const int n = RBETA;
    const double PI = 3.14159265358979323846;
    double x = -cos(PI * (i + 0.75) / (n + 0.5));     // ascending nodes
    for (int it = 0; it < 6; ++it) {
        double s0 = 1.0, s1 = x;                      // S_0, S_1
        for (int k = 1; k < n; ++k) {
            double dk = (double)k;
            double a  = fma(2.0 * dk, x, x);          // (2k+1)x, off-chain
            double s2 = fma(a, s1, -(dk * dk) * s0);  // chain: mul+fma
            s0 = s1; s1 = s2;
            if (fabs(s1) > 0x1p500) { s1 *= 0x1p-500; s0 *= 0x1p-500; }
        }
        // P_n ∝ s1, P_{n-1} ∝ n*s0 (common scale cancels in the ratio)
        double num = (x * x - 1.0) * s1;
        double den = (double)n * fma(x, s1, -(double)n * s0);
        x -= num / den;
    }
    // associated Legendre + norms at y = x
    double P[LMAX + 1][LMAX + 1];
    P[0][0] = 1.0;
    double somx2 = sqrt(fmax(1.0 - x * x, 0.0));
    for (int m = 1; m <= LMAX; ++m) P[m][m] = -(2.0 * m - 1.0) * somx2 * P[m - 1][m - 1];
    for (int m = 0; m < LMAX; ++m)  P[m + 1][m] = (2.0 * m + 1.0) * x * P[m][m];
    for (int m = 0; m <= LMAX; ++m)
        for (int l = m + 2; l <= LMAX; ++l)
            P[l][m] = ((2.0 * l - 1.0) * x * P[l - 1][m] - (l + m - 1.0) * P[l - 2][m]) / (double)(l - m);
    const double FOURPI = 12.566370614359172;
    for (int l = 0; l <= LMAX; ++l) {
        for (int m = 0; m <= l; ++m) {
            double fr = 1.0;                          // (l-m)!/(l+m)!
            for (int k = l - m + 1; k <= l + m; ++k) fr /= (double)k;
            double N = sqrt((2.0 * l + 1.0) / FOURPI * fr);
            double w = N * P[l][m];
            if (m > 0) w *= 1.4142135623730951;
            sWtab[i * 21 + l * (l + 1) / 2 + m] = (float)w;
        }
    }
}

// ---------------------------------------------------------------------------
// K2: per-graph small path. One block per graph, 256 threads.
__global__ __launch_bounds__(256)
void k_small(const float* __restrict__ ne, const float* __restrict__ sp,
             const float* __restrict__ wrad, const float* __restrict__ wm1,
             const float* __restrict__ wm2,
             const float* __restrict__ wa0, const float* __restrict__ wa1,
             const float* __restrict__ wa2, const float* __restrict__ wa3,
             const float* __restrict__ wa4, const float* __restrict__ wa5,
             const int* __restrict__ focus, const int* __restrict__ tspec,
             float* __restrict__ out0, float* __restrict__ out3,
             float* __restrict__ ang_ws, float* __restrict__ rad_ws)
{
    __shared__ float s0[MUL];
    __shared__ float rr[NRAD];
    __shared__ float hh[MUL];
    __shared__ float rl[NRAD];
    __shared__ float sang[NCH * SH_DIM];

    const int g = blockIdx.x;
    const int tid = threadIdx.x;
    const int fi = focus[g];
    const int ts = tspec[g];
    const float rs128 = 0.08838834764831845f;   // 1/sqrt(128)
    const float rs64  = 0.125f;                 // 1/sqrt(64)

    if (tid < MUL) s0[tid] = ne[(size_t)fi * EMB_DIM + tid] * sp[ts * NIRR + tid];
    __syncthreads();

    if (tid < NRAD) {
        float acc = 0.f;
        for (int k = 0; k < MUL; ++k) acc += s0[k] * wrad[k * NRAD + tid];
        rr[tid] = acc * rs128;
    }
    __syncthreads();

    if (tid < MUL) {
        float acc = 0.f;
        for (int j = 0; j < NRAD; ++j) acc += rr[j] * wm1[j * MUL + tid];
        float x = acc * rs64;
        hh[tid] = fmaxf(x, 0.f) + log1pf(expf(-fabsf(x)));   // stable softplus
    }
    __syncthreads();

    if (tid < NRAD) {
        float acc = 0.f;
        for (int k = 0; k < MUL; ++k) acc += hh[k] * wm2[k * NRAD + tid];
        float v = acc * rs128;
        rl[tid] = v;
        out3[g * NRAD + tid] = v;
        rad_ws[g * NRAD + tid] = v;
    }

    const float* WA[6] = {wa0, wa1, wa2, wa3, wa4, wa5};
    for (int t = tid; t < NCH * SH_DIM; t += blockDim.x) {
        int c = t / SH_DIM, kk = t % SH_DIM;
        int l = 0;
        while ((l + 1) * (l + 1) <= kk) ++l;
        int j = kk - l * l;
        int d = 2 * l + 1;
        const float* w  = WA[l];
        const float* nb = ne + (size_t)fi * EMB_DIM + MUL * l * l + j;
        const float* sb = sp + ts * NIRR + MUL * l;
        float acc = 0.f;
        for (int k = 0; k < MUL; ++k) acc += nb[k * d] * sb[k] * w[k * NCH + c];
        float v = acc * rs128;
        sang[t] = v;
        ang_ws[g * (NCH * SH_DIM) + t] = v;
    }
    __syncthreads();

    for (int t = tid; t < NCH * NRAD * SH_DIM; t += blockDim.x) {
        int kk = t % SH_DIM;
        int r  = (t / SH_DIM) % NRAD;
        int c  = t / (SH_DIM * NRAD);
        float v = sang[c * SH_DIM + kk];
        if (kk == 0) v += rl[r];
        out0[(size_t)g * (NCH * NRAD * SH_DIM) + t] = v;
    }
}

// ---------------------------------------------------------------------------
// K3: fused angular synthesis + logsumexp + radial broadcast.
// Block = (beta, g). Computes angular_logits row (359) in registers, writes
// out2, then streams out1[g,r,beta,:] = v + rad[g,r]*B00 for r=0..63.
__global__ __launch_bounds__(256)
void k_main(const float* __restrict__ sWtab, const float* __restrict__ ang_ws,
            const float* __restrict__ rad_ws,
            float* __restrict__ out1, float* __restrict__ out2)
{
    __shared__ float sW[21];
    __shared__ float sAng[NCH * SH_DIM];
    __shared__ float sF[NCH][11];
    __shared__ float sRad[NRAD];

    const int beta = blockIdx.x;
    const int g    = blockIdx.y;
    const int tid  = threadIdx.x;

    // full strided load: ALL 144 sAng elements covered (round-2 bug: only 128 were)
    for (int t = tid; t < NCH * SH_DIM; t += 256)
        sAng[t] = ang_ws[g * (NCH * SH_DIM) + t];
    if (tid < 21) sW[tid] = sWtab[beta * 21 + tid];
    if (tid >= 192)
        sRad[tid - 192] = rad_ws[g * NRAD + (tid - 192)] * 0.28209479177387814f;
    __syncthreads();

    if (tid < NCH * 11) {
        int c = tid / 11, j = tid % 11;
        float acc = 0.f;
        if (j == 0) {
            for (int l = 0; l <= LMAX; ++l)
                acc += sAng[c * SH_DIM + l * l + l] * sW[l * (l + 1) / 2];
        } else if (j <= 5) {
            int m = j;
            for (int l = m; l <= LMAX; ++l)
                acc += sAng[c * SH_DIM + l * l + l + m] * sW[l * (l + 1) / 2 + m];
        } else {
            int m = j - 5;
            for (int l = m; l <= LMAX; ++l)
                acc += sAng[c * SH_DIM + l * l + l - m] * sW[l * (l + 1) / 2 + m];
        }
        sF[c][j] = acc;
    }
    __syncthreads();

    // each thread handles alpha = tid and tid+256 (second only if < 359)
    const float dalpha = 6.283185307179586f / 359.0f;
    float v[2];
    #pragma unroll
    for (int half = 0; half < 2; ++half) {
        int a = tid + half * 256;
        if (a >= RALPHA) { v[half] = 0.f; continue; }
        float alpha = dalpha * (float)a;
        float s1, c1;
        __sincosf(alpha, &s1, &c1);
        float t0 = sF[0][0], t1 = sF[1][0], t2 = sF[2][0], t3 = sF[3][0];
        float cm = c1, sm = s1;
        #pragma unroll
        for (int m = 1; m <= 5; ++m) {
            t0 += sF[0][m] * cm + sF[0][5 + m] * sm;
            t1 += sF[1][m] * cm + sF[1][5 + m] * sm;
            t2 += sF[2][m] * cm + sF[2][5 + m] * sm;
            t3 += sF[3][m] * cm + sF[3][5 + m] * sm;
            float cn = cm * c1 - sm * s1;
            float sn = sm * c1 + cm * s1;
            cm = cn; sm = sn;
        }
        float mx = fmaxf(fmaxf(t0, t1), fmaxf(t2, t3));
        float s = expf(t0 - mx) + expf(t1 - mx) + expf(t2 - mx) + expf(t3 - mx);
        v[half] = mx + logf(s);
        out2[(size_t)g * GRID_BA + beta * RALPHA + a] = v[half];
    }

    // stream out1: 64 radii x 359 alphas, pure write
    const int second = (tid + 256 < RALPHA) ? 1 : 0;
    size_t base = ((size_t)(g * NRAD) * RBETA + beta) * RALPHA;
    #pragma unroll 4
    for (int r = 0; r < NRAD; ++r) {
        float rc = sRad[r];
        float* row = out1 + base + (size_t)r * GRID_BA;
        row[tid] = v[0] + rc;
        if (second) row[tid + 256] = v[1] + rc;
    }
}

// ---------------------------------------------------------------------------
extern "C" void kernel_launch(void* const* d_in, const int* in_sizes, int n_in,
                              void* d_out, int out_size, void* d_ws, size_t ws_size,
                              hipStream_t stream) {
    const float* ne   = (const float*)d_in[0];
    const float* sp   = (const float*)d_in[1];
    const float* wrad = (const float*)d_in[2];
    const float* wm1  = (const float*)d_in[3];
    const float* wm2  = (const float*)d_in[4];
    const float* wa0  = (const float*)d_in[5];
    const float* wa1  = (const float*)d_in[6];
    const float* wa2  = (const float*)d_in[7];
    const float* wa3  = (const float*)d_in[8];
    const float* wa4  = (const float*)d_in[9];
    const float* wa5  = (const float*)d_in[10];
    const int* focus  = (const int*)d_in[11];
    const int* tspec  = (const int*)d_in[12];

    float* out  = (float*)d_out;
    float* out0 = out + OUT0_OFF;
    float* out1 = out + OUT1_OFF;
    float* out2 = out + OUT2_OFF;
    float* out3 = out + OUT3_OFF;

    float* sWtab  = (float*)d_ws;                           // 180*21 floats
    float* ang_ws = (float*)((char*)d_ws + 16384);          // 16*144 floats
    float* rad_ws = (float*)((char*)d_ws + 26624);          // 16*64 floats

    hipLaunchKernelGGL(k_prep, dim3(1), dim3(192), 0, stream, sWtab);
    hipLaunchKernelGGL(k_small, dim3(NGRAPH), dim3(256), 0, stream,
                       ne, sp, wrad, wm1, wm2, wa0, wa1, wa2, wa3, wa4, wa5,
                       focus, tspec, out0, out3, ang_ws, rad_ws);
    hipLaunchKernelGGL(k_main, dim3(RBETA, NGRAPH), dim3(256), 0, stream,
                       sWtab, ang_ws, rad_ws, out1, out2);
}